// Round 20
// baseline (66.156 us; speedup 1.0000x reference)
//
#include <hip/hip_runtime.h>
#include <math.h>

// out[b,oc,y,x] = max_t min(p_t, k_t), p = channel-max(32) of x, OOB=-inf.
// x (16,32,256,256) f32, k (32,5,5) f32, out (16,32,256,256) f32.
//
// r15 champion structure (fused tile + sorted-tap early exit, 6.25 TB/s path
// ceiling) with a 64x16 tile: halo read amplification 1.5625x -> 1.328x
// (341 -> 313 MB total path bytes). Same 256-thread blocks / (256,2) bounds.

#define BATCH 16
#define CH    32
#define OCH   32
#define HH    256
#define WW    256
#define HWSZ  (HH * WW)
#define TW    64
#define TH    16
#define LH    20              // TH + 4
#define LW    76              // 72 data cols + 4 pad (16B-aligned granules)
#define NWG   (BATCH * (HH / TH) * (WW / TW))   // 1024

typedef float floatx4 __attribute__((ext_vector_type(4)));

// ---- Kernel 0: rank taps (descending k), one block ----
__global__ void sort_taps_kernel(const float* __restrict__ kk, float2* __restrict__ ent) {
    int t = threadIdx.x;
    if (t >= OCH * 25) return;
    int oc = t / 25, i = t % 25;
    float ki = kk[oc * 25 + i];
    int rank = 0;
#pragma unroll
    for (int j = 0; j < 25; ++j) {
        float kj = kk[oc * 25 + j];
        rank += (kj > ki) || (kj == ki && j < i);
    }
    int dy = i / 5, dx = i % 5;
    int off = 4 * (dy * LW + dx);                 // byte offset in halo-tile walk
    ent[oc * 26 + rank] = make_float2(ki, __int_as_float(off));
    if (i == 0) ent[oc * 26 + 25] = make_float2(-INFINITY, __int_as_float(0));
}

__global__ __launch_bounds__(256, 2) void fused_maxmin_kernel(const float* __restrict__ x,
                                                              const float2* __restrict__ gent,
                                                              float* __restrict__ out) {
    __shared__ float xmt[LH][LW];
    __shared__ float2 ent[OCH * 26];
    int tid = threadIdx.x;
    int bid = blockIdx.x;
    int swz = (bid & 7) * (NWG >> 3) + (bid >> 3);   // XCD-chunked, bijective
    int b   = swz >> 6;                              // 64 tiles/batch
    int t2  = swz & 63;
    int ty  = t2 >> 2;                               // 0..15 (16-row bands)
    int tx  = t2 & 3;                                // 0..3  (64-col bands)

    const float NI = -INFINITY;

    for (int i = tid; i < OCH * 26; i += 256) ent[i] = gent[i];

    // ---- Phase 1: channel max of 20 rows x 18 float4 granules (360) ----
    for (int g = tid; g < 18 * LH; g += 256) {
        int pr = g / 18;
        int pc = g % 18;
        int c4 = tx * 16 - 1 + pc;                   // global float4 col
        int rw = ty * TH - 2 + pr;                   // global row
        bool valid = (c4 >= 0) && (c4 < WW / 4) && (rw >= 0) && (rw < HH);
        int c4c = c4 < 0 ? 0 : (c4 > WW / 4 - 1 ? WW / 4 - 1 : c4);
        int rwc = rw < 0 ? 0 : (rw > HH - 1 ? HH - 1 : rw);
        const float4* src = (const float4*)x + (size_t)b * CH * (HWSZ / 4)
                          + (size_t)rwc * (WW / 4) + c4c;
        float4 m = src[0];
#pragma unroll
        for (int c = 1; c < CH; ++c) {
            float4 v = src[(size_t)c * (HWSZ / 4)];
            m.x = fmaxf(m.x, v.x);
            m.y = fmaxf(m.y, v.y);
            m.z = fmaxf(m.z, v.z);
            m.w = fmaxf(m.w, v.w);
        }
        if (!valid) { m.x = NI; m.y = NI; m.z = NI; m.w = NI; }
        *(float4*)&xmt[pr][4 * pc] = m;              // LW%4==0 -> 16B aligned
    }
    __syncthreads();

    // ---- Phase 2: sorted-tap early-exit scan ----
    // lane = 4 px (xg of 16) x 4 rows (rg of 4); wave = 8 oc.
    int xg = tid & 15;
    int rg = (tid >> 4) & 3;
    int wv = __builtin_amdgcn_readfirstlane(tid >> 6);   // oc 8wv..8wv+7
    int R0 = rg * 4;
    int X0 = 4 * xg;

    // Output (R0+rr, X0+j), tap (dy,dx) -> LDS[R0+rr+dy][X0+j+dx+2]
    // (halo origin = global x - 4, y - 2).
    const char* wb0 = (const char*)&xmt[R0 + 0][X0 + 2];
    const char* wb1 = (const char*)&xmt[R0 + 1][X0 + 2];
    const char* wb2 = (const char*)&xmt[R0 + 2][X0 + 2];
    const char* wb3 = (const char*)&xmt[R0 + 3][X0 + 2];

    size_t obase = (size_t)(b * OCH + wv * 8) * HWSZ
                 + (size_t)(ty * TH + R0) * WW + tx * TW + X0;

    for (int o = 0; o < 8; ++o) {
        const float2* E = &ent[(wv * 8 + o) * 26];
        float a00 = NI, a01 = NI, a02 = NI, a03 = NI;
        float a10 = NI, a11 = NI, a12 = NI, a13 = NI;
        float a20 = NI, a21 = NI, a22 = NI, a23 = NI;
        float a30 = NI, a31 = NI, a32 = NI, a33 = NI;

        for (int i = 0; i < 25; ++i) {
            float2 e  = E[i];                        // uniform -> LDS broadcast
            float  kn = E[i + 1].x;
            float  kv = e.x;
            int    off = __float_as_int(e.y);
            const float* p0 = (const float*)(wb0 + off);
            const float* p1 = (const float*)(wb1 + off);
            const float* p2 = (const float*)(wb2 + off);
            const float* p3 = (const float*)(wb3 + off);
            a00 = fmaxf(a00, fminf(p0[0], kv));
            a01 = fmaxf(a01, fminf(p0[1], kv));
            a02 = fmaxf(a02, fminf(p0[2], kv));
            a03 = fmaxf(a03, fminf(p0[3], kv));
            a10 = fmaxf(a10, fminf(p1[0], kv));
            a11 = fmaxf(a11, fminf(p1[1], kv));
            a12 = fmaxf(a12, fminf(p1[2], kv));
            a13 = fmaxf(a13, fminf(p1[3], kv));
            a20 = fmaxf(a20, fminf(p2[0], kv));
            a21 = fmaxf(a21, fminf(p2[1], kv));
            a22 = fmaxf(a22, fminf(p2[2], kv));
            a23 = fmaxf(a23, fminf(p2[3], kv));
            a30 = fmaxf(a30, fminf(p3[0], kv));
            a31 = fmaxf(a31, fminf(p3[1], kv));
            a32 = fmaxf(a32, fminf(p3[2], kv));
            a33 = fmaxf(a33, fminf(p3[3], kv));
            float mn = fminf(
                fminf(fminf(fminf(a00, a01), fminf(a02, a03)),
                      fminf(fminf(a10, a11), fminf(a12, a13))),
                fminf(fminf(fminf(a20, a21), fminf(a22, a23)),
                      fminf(fminf(a30, a31), fminf(a32, a33))));
            if (__all(mn >= kn)) break;              // remaining cands <= kn <= a
        }

        float* op = out + obase + (size_t)o * HWSZ;
        floatx4 o0 = { a00, a01, a02, a03 };
        floatx4 o1 = { a10, a11, a12, a13 };
        floatx4 o2 = { a20, a21, a22, a23 };
        floatx4 o3 = { a30, a31, a32, a33 };
        __builtin_nontemporal_store(o0, (floatx4*)(op + 0 * WW));
        __builtin_nontemporal_store(o1, (floatx4*)(op + 1 * WW));
        __builtin_nontemporal_store(o2, (floatx4*)(op + 2 * WW));
        __builtin_nontemporal_store(o3, (floatx4*)(op + 3 * WW));
    }
}

extern "C" void kernel_launch(void* const* d_in, const int* in_sizes, int n_in,
                              void* d_out, int out_size, void* d_ws, size_t ws_size,
                              hipStream_t stream) {
    const float* x  = (const float*)d_in[0];
    const float* kk = (const float*)d_in[1];
    float* out      = (float*)d_out;
    float2* ent     = (float2*)d_ws;   // 6656 B

    sort_taps_kernel<<<1, OCH * 25, 0, stream>>>(kk, ent);
    fused_maxmin_kernel<<<NWG, 256, 0, stream>>>(x, ent, out);
}

// Round 21
// 54.483 us; speedup vs baseline: 1.2143x; 1.2143x over previous
//
#include <hip/hip_runtime.h>
#include <math.h>

// Fused maxmin-conv with SORTED-TAP EARLY EXIT.  (champion, r15: 54.6us)
// out[b,oc,y,x] = max_{t} min(p_t, k_t) over 25 taps. Process taps in
// descending k order; stop when a >= k_next (remaining cands <= k_next <= a).
// EXACT (same max of same mins). With p = chanmax of 32 gaussians (~2.5) and
// |k| <= ~0.5, interior pixels exit after 1 step.
//
// Runs at the ~6.25 TB/s vector-memory path ceiling for its 341 MB of moved
// bytes (= m13 copy ceiling); VALU 9%, HBM 29% -> path-bound, at roofline.

#define BATCH 16
#define CH    32
#define OCH   32
#define HH    256
#define WW    256
#define HWSZ  (HH * WW)
#define TW    32
#define TH    16
#define LH    20              // TH + 4
#define LW    42              // LDS tile stride (floats)
#define NWG   (BATCH * (HH / TH) * (WW / TW))   // 2048

typedef float floatx4 __attribute__((ext_vector_type(4)));

// ---- Kernel 1: sort taps by rank (one block, 800 threads) ----
__global__ void sort_taps_kernel(const float* __restrict__ kk, float2* __restrict__ ent) {
    int t = threadIdx.x;
    if (t >= OCH * 25) return;
    int oc = t / 25, i = t % 25;
    float ki = kk[oc * 25 + i];
    int rank = 0;
#pragma unroll
    for (int j = 0; j < 25; ++j) {
        float kj = kk[oc * 25 + j];
        rank += (kj > ki) || (kj == ki && j < i);
    }
    int dy = i / 5, dx = i % 5;
    int off = 4 * (dy * LW + dx);                 // byte offset within LDS tile walk
    ent[oc * 26 + rank] = make_float2(ki, __int_as_float(off));
    if (i == 0) ent[oc * 26 + 25] = make_float2(-INFINITY, __int_as_float(0));
}

__global__ __launch_bounds__(256, 2) void fused_maxmin_kernel(const float* __restrict__ x,
                                                              const float2* __restrict__ gent,
                                                              float* __restrict__ out) {
    __shared__ float xmt[LH][LW];
    __shared__ float2 ent[OCH * 26];
    int tid = threadIdx.x;
    int bid = blockIdx.x;
    int swz = (bid & 7) * (NWG >> 3) + (bid >> 3);   // XCD-chunked, bijective
    int b   = swz >> 7;
    int t2  = swz & 127;
    int ty  = t2 >> 3;
    int tx  = t2 & 7;

    const float NI = -INFINITY;

    // stage sorted tap entries (832 float2, coalesced)
    for (int i = tid; i < OCH * 26; i += 256) ent[i] = gent[i];

    // ---- Phase 1: channel max of 20 rows x 10 float4 granules ----
    if (tid < 200) {
        int pr = tid / 10;
        int pc = tid % 10;
        int c4 = tx * 8 - 1 + pc;
        int rw = ty * TH - 2 + pr;
        bool valid = (c4 >= 0) && (c4 < WW / 4) && (rw >= 0) && (rw < HH);
        int c4c = c4 < 0 ? 0 : (c4 > WW / 4 - 1 ? WW / 4 - 1 : c4);
        int rwc = rw < 0 ? 0 : (rw > HH - 1 ? HH - 1 : rw);
        const float4* src = (const float4*)x + (size_t)b * CH * (HWSZ / 4)
                          + (size_t)rwc * (WW / 4) + c4c;
        float4 m = src[0];
#pragma unroll
        for (int c = 1; c < CH; ++c) {
            float4 v = src[(size_t)c * (HWSZ / 4)];
            m.x = fmaxf(m.x, v.x);
            m.y = fmaxf(m.y, v.y);
            m.z = fmaxf(m.z, v.z);
            m.w = fmaxf(m.w, v.w);
        }
        if (!valid) { m.x = NI; m.y = NI; m.z = NI; m.w = NI; }
        *(float2*)&xmt[pr][4 * pc]     = make_float2(m.x, m.y);
        *(float2*)&xmt[pr][4 * pc + 2] = make_float2(m.z, m.w);
    }
    __syncthreads();

    // ---- Phase 2: sorted-tap scan ----
    int xg = tid & 7;                                // 4 px
    int rg = (tid >> 3) & 7;                         // 2 rows
    int wv = __builtin_amdgcn_readfirstlane(tid >> 6);   // wave -> oc 8wv..8wv+7

    // Tap walk bases: output (r,j) reads (const char*)rp[r] + off + 4j.
    const char* r0p = (const char*)&xmt[2 * rg][4 * xg + 2];
    const char* r1p = (const char*)&xmt[2 * rg + 1][4 * xg + 2];

    size_t obase = (size_t)(b * OCH + wv * 8) * HWSZ
                 + (size_t)(ty * TH + 2 * rg) * WW + tx * TW + 4 * xg;

    for (int o = 0; o < 8; ++o) {
        const float2* E = &ent[(wv * 8 + o) * 26];
        float a00 = NI, a01 = NI, a02 = NI, a03 = NI;
        float a10 = NI, a11 = NI, a12 = NI, a13 = NI;

        for (int i = 0; i < 25; ++i) {
            float2 e  = E[i];                        // uniform -> LDS broadcast
            float  kn = E[i + 1].x;
            float  kv = e.x;
            int    off = __float_as_int(e.y);
            const float* p0 = (const float*)(r0p + off);
            const float* p1 = (const float*)(r1p + off);
            a00 = fmaxf(a00, fminf(p0[0], kv));
            a01 = fmaxf(a01, fminf(p0[1], kv));
            a02 = fmaxf(a02, fminf(p0[2], kv));
            a03 = fmaxf(a03, fminf(p0[3], kv));
            a10 = fmaxf(a10, fminf(p1[0], kv));
            a11 = fmaxf(a11, fminf(p1[1], kv));
            a12 = fmaxf(a12, fminf(p1[2], kv));
            a13 = fmaxf(a13, fminf(p1[3], kv));
            float mn = fminf(fminf(fminf(a00, a01), fminf(a02, a03)),
                             fminf(fminf(a10, a11), fminf(a12, a13)));
            if (__all(mn >= kn)) break;              // remaining cands <= kn <= a
        }

        float* op = out + obase + (size_t)o * HWSZ;
        floatx4 o0 = { a00, a01, a02, a03 };
        floatx4 o1 = { a10, a11, a12, a13 };
        __builtin_nontemporal_store(o0, (floatx4*)op);
        __builtin_nontemporal_store(o1, (floatx4*)(op + WW));
    }
}

extern "C" void kernel_launch(void* const* d_in, const int* in_sizes, int n_in,
                              void* d_out, int out_size, void* d_ws, size_t ws_size,
                              hipStream_t stream) {
    const float* x  = (const float*)d_in[0];
    const float* kk = (const float*)d_in[1];
    float* out      = (float*)d_out;
    float2* ent     = (float2*)d_ws;   // 32*26*8 = 6656 B

    sort_taps_kernel<<<1, OCH * 25, 0, stream>>>(kk, ent);
    fused_maxmin_kernel<<<NWG, 256, 0, stream>>>(x, ent, out);
}